// Round 8
// baseline (17.464 us; speedup 1.0000x reference)
//
#include <hip/hip_runtime.h>

// 3x3 median blur, BORDER_REPLICATE, NHWC float32. B=64, H=224, W=224, C=3.
// R7: 8 rows/thread with rolling 3-row register window. Loads 10 input rows
// per 8 output rows (1.125x read amplification, was 1.5x at 4 rows/thread).
// All rolling-buffer indices are compile-time under full unroll (rule #20:
// runtime-indexed locals go to scratch). Chunked XCD swizzle: 1176 blocks =
// 8 * 147, each XCD band = exactly 8 whole images. Nontemporal stores kept
// (R5, -1.8us); nontemporal loads reverted (R6, no effect).

typedef float f32x4 __attribute__((ext_vector_type(4)));

__device__ __forceinline__ float min3f(float a, float b, float c) {
    return fminf(fminf(a, b), c);           // v_min3_f32
}
__device__ __forceinline__ float max3f(float a, float b, float c) {
    return fmaxf(fmaxf(a, b), c);           // v_max3_f32
}
__device__ __forceinline__ float med3f(float a, float b, float c) {
    return __builtin_amdgcn_fmed3f(a, b, c); // v_med3_f32
}

struct Row { float q[10]; };

__global__ __launch_bounds__(256) void median3x3_r7(
    const float* __restrict__ in, float* __restrict__ out)
{
    const int W = 224, H = 224;
    const int ROWF   = W * 3;        // 672 floats per row
    const int CHUNKS = ROWF / 4;     // 168 float4 chunks per row
    const int ROWS   = 8;            // output rows per thread
    const int GROUPS = H / ROWS;     // 28 row-groups per image
    const int NXCD   = 8;
    const int BAND   = 1176 / NXCD;  // 147 blocks per XCD band

    int bid  = blockIdx.x;
    int virt = (bid & (NXCD - 1)) * BAND + (bid >> 3);

    int t    = virt * 256 + threadIdx.x;
    int ci   = t % CHUNKS;
    int rest = t / CHUNKS;
    int g    = rest % GROUPS;        // row group within image
    int b    = rest / GROUPS;        // image index
    int r0   = g * ROWS;             // first output row of this thread

    const float* img  = in  + (size_t)b * H * ROWF;
    float*       oimg = out + (size_t)b * H * ROWF;

    const int li  = (ci > 0)          ? ci - 1 : 0;
    const int riq = (ci < CHUNKS - 1) ? ci + 1 : CHUNKS - 1;
    const bool first = (ci == 0), last = (ci == CHUNKS - 1);

    // Load input row h (clamped) as the 10 chunk-relative columns -3..6.
    auto loadRow = [&](int h) -> Row {
        h = (h < 0) ? 0 : ((h > H - 1) ? H - 1 : h);
        const f32x4* rp = (const f32x4*)(img + (size_t)h * ROWF);
        f32x4 L = rp[li];
        f32x4 M = rp[ci];
        f32x4 R = rp[riq];
        Row d;
        d.q[0] = first ? M.x : L.y;   // pos -3
        d.q[1] = first ? M.y : L.z;   // pos -2
        d.q[2] = first ? M.z : L.w;   // pos -1
        d.q[3] = M.x;
        d.q[4] = M.y;
        d.q[5] = M.z;
        d.q[6] = M.w;
        d.q[7] = last ? M.y : R.x;    // pos 4
        d.q[8] = last ? M.z : R.y;    // pos 5
        d.q[9] = last ? M.w : R.z;    // pos 6
        return d;
    };

    Row v[3];
    v[0] = loadRow(r0 - 1);
    v[1] = loadRow(r0);

    #pragma unroll
    for (int k = 0; k < ROWS; ++k) {
        // Window for output row r0+k: rows r0+k-1, r0+k, r0+k+1.
        v[(k + 2) % 3] = loadRow(r0 + k + 1);
        const Row& A = v[k % 3];
        const Row& B = v[(k + 1) % 3];
        const Row& C = v[(k + 2) % 3];

        float lo[10], me[10], hi[10];
        #pragma unroll
        for (int q = 0; q < 10; ++q) {
            lo[q] = min3f(A.q[q], B.q[q], C.q[q]);
            me[q] = med3f(A.q[q], B.q[q], C.q[q]);
            hi[q] = max3f(A.q[q], B.q[q], C.q[q]);
        }
        f32x4 o;
        o.x = med3f(max3f(lo[0], lo[3], lo[6]),
                    med3f(me[0], me[3], me[6]),
                    min3f(hi[0], hi[3], hi[6]));
        o.y = med3f(max3f(lo[1], lo[4], lo[7]),
                    med3f(me[1], me[4], me[7]),
                    min3f(hi[1], hi[4], hi[7]));
        o.z = med3f(max3f(lo[2], lo[5], lo[8]),
                    med3f(me[2], me[5], me[8]),
                    min3f(hi[2], hi[5], hi[8]));
        o.w = med3f(max3f(lo[3], lo[6], lo[9]),
                    med3f(me[3], me[6], me[9]),
                    min3f(hi[3], hi[6], hi[9]));
        f32x4* dst = (f32x4*)(oimg + (size_t)(r0 + k) * ROWF) + ci;
        __builtin_nontemporal_store(o, dst);
    }
}

extern "C" void kernel_launch(void* const* d_in, const int* in_sizes, int n_in,
                              void* d_out, int out_size, void* d_ws, size_t ws_size,
                              hipStream_t stream) {
    const float* x = (const float*)d_in[0];
    float* out     = (float*)d_out;

    // total threads = 64 * 28 * 168 = 301,056 = 1176 blocks * 256 (exact)
    const int grid  = 1176;
    const int block = 256;
    median3x3_r7<<<grid, block, 0, stream>>>(x, out);
}